// Round 10
// baseline (87.395 us; speedup 1.0000x reference)
//
#include <hip/hip_runtime.h>

// YOLO v1 loss on MI355X — round 10.
// Direct-load family with FORCED memory-level parallelism: all 16 float4
// loads per thread are pinned in flight by an asm vmcnt(0) memory clobber
// (loads cannot sink past it -> all issue back-to-back; R8's VGPR=40 showed
// the compiler otherwise batches them into dependent groups, collapsing MLP).
// Wave-parity layout (R8) keeps the overlapping 240-B pair windows
// co-resident on a CU -> HBM fetch stays ~60 MB (verified R8).
// Reduction fused: per-block partials -> ws, __threadfence + atomic counter,
// last block reduces and writes out (counter zeroed via 4-B memsetAsync).
// bounding_boxes (8192,7,7,30) f32, ground_truth (8192,7,7,30) f32.
// Output: 6 float32 scalars.

#define NCELLS (8192 * 49)   // 401408
#define NPAIRS (NCELLS / 2)  // 200704
#define BLK 256
#define PPB 128              // pairs per block (4 waves: 2 parity-pairs)
#define NBLK (NPAIRS / PPB)  // 1568
#define CNT_OFF (6 * NBLK)   // counter at ws[9408]

__device__ __forceinline__ float iou_one(const float* __restrict__ B,
                                         const float* __restrict__ G,
                                         float fx, float fy) {
    float px = truncf((B[0] + fx) * 64.0f);
    float py = truncf((B[1] + fy) * 64.0f);
    float pw = truncf(B[2] * 448.0f);
    float ph = truncf(B[3] * 448.0f);
    float x1 = fmaxf(0.0f, px - pw * 0.5f);
    float y1 = fmaxf(0.0f, py - ph * 0.5f);
    float x2 = fminf(447.0f, px + pw * 0.5f);
    float y2 = fminf(447.0f, py + ph * 0.5f);
    float parea = (x2 - x1) * (y2 - y1);
    float lx = fmaxf(x1, G[5]);
    float rx = fminf(x2, G[7]);
    float uy = fmaxf(y1, G[6]);
    float dy = fminf(y2, G[8]);
    float inter = (rx - lx) * (dy - uy);
    bool valid = (rx >= lx) && (dy >= uy);
    return valid ? inter / (parea + G[9] - inter) : 0.0f;
}

// One cell; OFF compile-time (0 even / 2 odd) -> static register indexing.
template <int OFF>
__device__ __forceinline__ void do_cell(const float4* __restrict__ b4,
                                        const float4* __restrict__ g4,
                                        size_t f4idx, int cell, float acc[6]) {
    float vb[32], vg[32];
#pragma unroll
    for (int i = 0; i < 8; ++i) {
        *(float4*)(vb + 4 * i) = b4[f4idx + i];
        *(float4*)(vg + 4 * i) = g4[f4idx + i];
    }
    // Pin all 16 loads in flight: loads cannot sink past a memory clobber.
    asm volatile("s_waitcnt vmcnt(0)" ::: "memory");

    const float* B = vb + OFF;
    const float* G = vg + OFF;

    int rem = cell % 49;
    int gy = rem / 7;
    int gx = rem - gy * 7;
    float fx = (float)gx, fy = (float)gy;

    float iou1 = iou_one(B, G, fx, fy);
    float iou2 = iou_one(B + 5, G, fx, fy);
    bool r1 = iou1 > iou2;
    const float* P = r1 ? B : (B + 5);   // responsible box
    const float* Nb = r1 ? (B + 5) : B;  // other box
    float iou = r1 ? iou1 : iou2;

    float fm = (rintf(G[4]) != 0.0f) ? 1.0f : 0.0f;
    float noobj = 0.5f * (B[4] * B[4] + B[9] * B[9]);

    float dx = P[0] - G[0];
    float dyv = P[1] - G[1];
    float dw = sqrtf(P[2]) - sqrtf(G[2]);
    float dh = sqrtf(P[3]) - sqrtf(G[3]);
    float coord = 5.0f * (dx * dx + dyv * dyv + dw * dw + dh * dh);

    float dc = P[4] - iou;
    float conf = dc * dc + 0.5f * Nb[4] * Nb[4];

    float cls = 0.f;
#pragma unroll
    for (int k = 0; k < 20; ++k) {
        float d = G[10 + k] - B[10 + k];
        cls += d * d;
    }

    float ifm = 1.0f - fm;
    acc[0] += fm * (coord + conf + cls) + ifm * noobj;
    acc[1] += fm * coord;
    acc[2] += fm * conf + ifm * noobj;
    acc[3] += fm * cls;
    acc[4] += fm * iou;
    acc[5] += fm;
}

__global__ __launch_bounds__(256, 4) void yolo_v1_loss_main(
    const float* __restrict__ bbf, const float* __restrict__ gtf,
    float* __restrict__ ws, float* __restrict__ out) {
    __shared__ float sRed[4][6];
    __shared__ int sLast;

    const int tid = threadIdx.x;
    const int lane = tid & 63;
    const int w = tid >> 6;    // 0..3
    const int parity = w & 1;  // wave-uniform
    // waves 0,1 -> pairs [base, base+64); waves 2,3 -> [base+64, base+128)
    const size_t pu = (size_t)blockIdx.x * PPB + (size_t)(w >> 1) * 64 + lane;

    const float4* b4 = (const float4*)bbf;
    const float4* g4 = (const float4*)gtf;

    float acc[6] = {0.f, 0.f, 0.f, 0.f, 0.f, 0.f};

    if (parity == 0) {
        // cell 2u: floats [60u, 60u+30) ⊂ f4 [15u, 15u+8), data at +0
        do_cell<0>(b4, g4, 15 * pu, (int)(2 * pu), acc);
    } else {
        // cell 2u+1: floats [60u+30, 60u+60) ⊂ f4 [15u+7, 15u+15), data at +2
        do_cell<2>(b4, g4, 15 * pu + 7, (int)(2 * pu + 1), acc);
    }

    // ---- wave reduce (64-wide) ----
#pragma unroll
    for (int off = 32; off > 0; off >>= 1) {
#pragma unroll
        for (int j = 0; j < 6; ++j) acc[j] += __shfl_down(acc[j], off);
    }
    if (lane == 0) {
#pragma unroll
        for (int j = 0; j < 6; ++j) sRed[w][j] = acc[j];
    }
    __syncthreads();

    // ---- block partials -> ws; last-block detection ----
    if (tid == 0) {
#pragma unroll
        for (int j = 0; j < 6; ++j)
            ws[j * NBLK + blockIdx.x] =
                sRed[0][j] + sRed[1][j] + sRed[2][j] + sRed[3][j];
        __threadfence();  // release: partials visible device-wide
        unsigned old = atomicAdd((unsigned*)(ws + CNT_OFF), 1u);
        sLast = (old == NBLK - 1);
    }
    __syncthreads();

    // ---- last block: final reduction (fixed order -> deterministic) ----
    if (sLast) {
        __threadfence();  // acquire: see all blocks' partials
#pragma unroll
        for (int j = 0; j < 6; ++j) {
            float s = 0.f;
            for (int i = tid; i < NBLK; i += BLK) s += ws[j * NBLK + i];
#pragma unroll
            for (int off = 32; off > 0; off >>= 1) s += __shfl_down(s, off);
            if (lane == 0) sRed[w][j] = s;
        }
        __syncthreads();
        if (tid == 0) {
#pragma unroll
            for (int j = 0; j < 6; ++j)
                out[j] = sRed[0][j] + sRed[1][j] + sRed[2][j] + sRed[3][j];
        }
    }
}

extern "C" void kernel_launch(void* const* d_in, const int* in_sizes, int n_in,
                              void* d_out, int out_size, void* d_ws,
                              size_t ws_size, hipStream_t stream) {
    const float* bb = (const float*)d_in[0];
    const float* gt = (const float*)d_in[1];
    float* out = (float*)d_out;
    float* ws = (float*)d_ws;
    // zero the arrival counter (graph-capture-safe async memset, 4 bytes)
    hipMemsetAsync(ws + CNT_OFF, 0, sizeof(unsigned), stream);
    yolo_v1_loss_main<<<NBLK, BLK, 0, stream>>>(bb, gt, ws, out);
}

// Round 11
// 58.970 us; speedup vs baseline: 1.4820x; 1.4820x over previous
//
#include <hip/hip_runtime.h>

// YOLO v1 loss on MI355X — round 11.
// R3 winner (pair-per-thread, 30 hoisted float4 loads, single code path) with:
//  (1) __launch_bounds__(256,3): VGPR cap ~170 (was 68) so the allocator can
//      keep ~2x more loads in flight; floor 12 waves/CU == grid limit
//      (3136 waves / 256 CU), so no occupancy cost.
//  (2) fused last-block reduction (validated in R10): no 2nd launch/gap.
// NO asm pins, NO parity templates (R7/8/10 lesson: they starve the
// allocator to 40 VGPR and serialize loads).
// bounding_boxes (8192,7,7,30) f32, ground_truth (8192,7,7,30) f32.
// Output: 6 float32 scalars.

#define NCELLS (8192 * 49)   // 401408
#define NPAIRS (NCELLS / 2)  // 200704
#define BLK 256
#define NBLK (NPAIRS / BLK)  // 784
#define CNT_OFF (6 * NBLK)   // counter at ws[4704]

__device__ __forceinline__ float iou_one(const float* __restrict__ B,
                                         const float* __restrict__ G,
                                         float fx, float fy) {
    float px = truncf((B[0] + fx) * 64.0f);
    float py = truncf((B[1] + fy) * 64.0f);
    float pw = truncf(B[2] * 448.0f);
    float ph = truncf(B[3] * 448.0f);
    float x1 = fmaxf(0.0f, px - pw * 0.5f);
    float y1 = fmaxf(0.0f, py - ph * 0.5f);
    float x2 = fminf(447.0f, px + pw * 0.5f);
    float y2 = fminf(447.0f, py + ph * 0.5f);
    float parea = (x2 - x1) * (y2 - y1);
    float lx = fmaxf(x1, G[5]);
    float rx = fminf(x2, G[7]);
    float uy = fmaxf(y1, G[6]);
    float dy = fminf(y2, G[8]);
    float inter = (rx - lx) * (dy - uy);
    bool valid = (rx >= lx) && (dy >= uy);
    return valid ? inter / (parea + G[9] - inter) : 0.0f;
}

__global__ __launch_bounds__(256, 3) void yolo_v1_loss_main(
    const float* __restrict__ bbf, const float* __restrict__ gtf,
    float* __restrict__ ws, float* __restrict__ out) {
    __shared__ float sRed[4][6];
    __shared__ int sLast;

    const int tid = threadIdx.x;
    const int lane = tid & 63;
    const int w = tid >> 6;
    const size_t pair = (size_t)blockIdx.x * BLK + tid;  // 0..NPAIRS-1

    const float4* pb = (const float4*)bbf + pair * 15;
    const float4* pg = (const float4*)gtf + pair * 15;

    // ---- hoist ALL loads: 30 independent float4 ----
    float vb[60], vg[60];
#pragma unroll
    for (int i = 0; i < 15; ++i) {
        *(float4*)(vb + 4 * i) = pb[i];
        *(float4*)(vg + 4 * i) = pg[i];
    }

    float acc[6] = {0.f, 0.f, 0.f, 0.f, 0.f, 0.f};

#pragma unroll
    for (int c = 0; c < 2; ++c) {
        const float* B = vb + 30 * c;
        const float* G = vg + 30 * c;

        int cell = (int)(pair * 2) + c;
        int rem = cell % 49;
        int gy = rem / 7;
        int gx = rem - gy * 7;
        float fx = (float)gx, fy = (float)gy;

        float iou1 = iou_one(B, G, fx, fy);
        float iou2 = iou_one(B + 5, G, fx, fy);
        bool r1 = iou1 > iou2;
        const float* P = r1 ? B : (B + 5);   // responsible box
        const float* Nb = r1 ? (B + 5) : B;  // other box
        float iou = r1 ? iou1 : iou2;

        float fm = (rintf(G[4]) != 0.0f) ? 1.0f : 0.0f;
        float noobj = 0.5f * (B[4] * B[4] + B[9] * B[9]);

        float dx = P[0] - G[0];
        float dyv = P[1] - G[1];
        float dw = sqrtf(P[2]) - sqrtf(G[2]);
        float dh = sqrtf(P[3]) - sqrtf(G[3]);
        float coord = 5.0f * (dx * dx + dyv * dyv + dw * dw + dh * dh);

        float dc = P[4] - iou;
        float conf = dc * dc + 0.5f * Nb[4] * Nb[4];

        float cls = 0.f;
#pragma unroll
        for (int k = 0; k < 20; ++k) {
            float d = G[10 + k] - B[10 + k];
            cls += d * d;
        }

        float ifm = 1.0f - fm;
        acc[0] += fm * (coord + conf + cls) + ifm * noobj;
        acc[1] += fm * coord;
        acc[2] += fm * conf + ifm * noobj;
        acc[3] += fm * cls;
        acc[4] += fm * iou;
        acc[5] += fm;
    }

    // ---- wave reduce (64-wide) ----
#pragma unroll
    for (int off = 32; off > 0; off >>= 1) {
#pragma unroll
        for (int j = 0; j < 6; ++j) acc[j] += __shfl_down(acc[j], off);
    }
    if (lane == 0) {
#pragma unroll
        for (int j = 0; j < 6; ++j) sRed[w][j] = acc[j];
    }
    __syncthreads();

    // ---- block partials -> ws; last-block detection ----
    if (tid == 0) {
#pragma unroll
        for (int j = 0; j < 6; ++j)
            ws[j * NBLK + blockIdx.x] =
                sRed[0][j] + sRed[1][j] + sRed[2][j] + sRed[3][j];
        __threadfence();  // release: partials visible device-wide
        unsigned old = atomicAdd((unsigned*)(ws + CNT_OFF), 1u);
        sLast = (old == NBLK - 1);
    }
    __syncthreads();

    // ---- last block: final reduction (fixed order -> deterministic) ----
    if (sLast) {
        __threadfence();  // acquire: see all blocks' partials
#pragma unroll
        for (int j = 0; j < 6; ++j) {
            float s = 0.f;
            for (int i = tid; i < NBLK; i += BLK) s += ws[j * NBLK + i];
#pragma unroll
            for (int off = 32; off > 0; off >>= 1) s += __shfl_down(s, off);
            if (lane == 0) sRed[w][j] = s;
        }
        __syncthreads();
        if (tid == 0) {
#pragma unroll
            for (int j = 0; j < 6; ++j)
                out[j] = sRed[0][j] + sRed[1][j] + sRed[2][j] + sRed[3][j];
        }
    }
}

extern "C" void kernel_launch(void* const* d_in, const int* in_sizes, int n_in,
                              void* d_out, int out_size, void* d_ws,
                              size_t ws_size, hipStream_t stream) {
    const float* bb = (const float*)d_in[0];
    const float* gt = (const float*)d_in[1];
    float* out = (float*)d_out;
    float* ws = (float*)d_ws;
    // zero the arrival counter (graph-capture-safe async memset, 4 bytes)
    hipMemsetAsync(ws + CNT_OFF, 0, sizeof(unsigned), stream);
    yolo_v1_loss_main<<<NBLK, BLK, 0, stream>>>(bb, gt, ws, out);
}